// Round 5
// baseline (554.616 us; speedup 1.0000x reference)
//
#include <hip/hip_runtime.h>
#include <hip/hip_fp16.h>

typedef _Float16 half8 __attribute__((ext_vector_type(8)));
typedef float floatx4 __attribute__((ext_vector_type(4)));

#define NHC 16            // head-col block (13 used + 3 pad)
#define WCOLS (128 + NHC) // 144 columns in extended W

// ---------------- QR: 3x3 Householder, LAPACK sgeqrf/sorgqr convention ----------------
__device__ inline void qr3_q(const double A[3][3], double Q[3][3]){
  double a[3][3];
#pragma unroll
  for (int r = 0; r < 3; r++)
#pragma unroll
    for (int c = 0; c < 3; c++) a[r][c] = A[r][c];

  double v1[3] = {1.0, 0.0, 0.0};
  double tau1 = 0.0;
  {
    double xn2 = a[1][0]*a[1][0] + a[2][0]*a[2][0];
    if (xn2 != 0.0){
      double alpha = a[0][0];
      double beta = -copysign(sqrt(alpha*alpha + xn2), alpha);
      tau1 = (beta - alpha) / beta;
      double inv = 1.0 / (alpha - beta);
      v1[1] = a[1][0] * inv;
      v1[2] = a[2][0] * inv;
#pragma unroll
      for (int c = 1; c < 3; c++){
        double w = a[0][c] + v1[1]*a[1][c] + v1[2]*a[2][c];
        double tw = tau1 * w;
        a[0][c] -= tw;
        a[1][c] -= tw * v1[1];
        a[2][c] -= tw * v1[2];
      }
    }
  }
  double tau2 = 0.0, v2 = 0.0;
  {
    double x2 = a[2][1];
    if (x2 != 0.0){
      double alpha = a[1][1];
      double beta = -copysign(sqrt(alpha*alpha + x2*x2), alpha);
      tau2 = (beta - alpha) / beta;
      v2 = x2 / (alpha - beta);
    }
  }
  double M[3][3] = {{1.0, 0.0, 0.0},
                    {0.0, 1.0 - tau2, -tau2*v2},
                    {0.0, -tau2*v2, 1.0 - tau2*v2*v2}};
#pragma unroll
  for (int c = 0; c < 3; c++){
    double w = v1[0]*M[0][c] + v1[1]*M[1][c] + v1[2]*M[2][c];
#pragma unroll
    for (int r = 0; r < 3; r++)
      Q[r][c] = M[r][c] - tau1 * v1[r] * w;
  }
}

// ---------------- SE(3) per-node epilogue (shared device body) ----------------
__device__ inline void se3_node(int n, const float* __restrict__ dsws,
                                const float* __restrict__ bc, const float* __restrict__ bR,
                                const float* __restrict__ bt, const float* __restrict__ pos_in,
                                float* __restrict__ pos_o, float* __restrict__ R_o,
                                float* __restrict__ t_o, int layer, int N){
  float ds[13];
#pragma unroll
  for (int c = 0; c < 13; c++) ds[c] = dsws[(size_t)c*N + n];

  double A[3][3], Q[3][3];
#pragma unroll
  for (int r = 0; r < 3; r++)
#pragma unroll
    for (int c = 0; c < 3; c++)
      A[r][c] = (double)ds[1 + r*3 + c] + (double)bR[r*3 + c];
  qr3_q(A, Q);

  double pd = (double)ds[0] + (double)bc[0];
#pragma unroll
  for (int c = 0; c < 3; c++){
    double base = (layer == 0) ? (double)pos_in[n*3 + c] : (double)pos_o[n*3 + c];
    pos_o[n*3 + c] = (float)(base + pd);
  }

  if (layer == 0){
#pragma unroll
    for (int r = 0; r < 3; r++)
#pragma unroll
      for (int c = 0; c < 3; c++)
        R_o[n*9 + r*3 + c] = (float)Q[r][c];
  } else {
    double Rold[3][3];
#pragma unroll
    for (int r = 0; r < 3; r++)
#pragma unroll
      for (int c = 0; c < 3; c++)
        Rold[r][c] = (double)R_o[n*9 + r*3 + c];
#pragma unroll
    for (int r = 0; r < 3; r++)
#pragma unroll
      for (int c = 0; c < 3; c++){
        double s = Q[r][0]*Rold[0][c] + Q[r][1]*Rold[1][c] + Q[r][2]*Rold[2][c];
        R_o[n*9 + r*3 + c] = (float)s;
      }
  }
#pragma unroll
  for (int c = 0; c < 3; c++){
    double base = (layer == 0) ? 0.0 : (double)t_o[n*3 + c];
    t_o[n*3 + c] = (float)(base + (double)ds[10 + c] + (double)bt[c]);
  }
}

// ---------------- fused count + weight prep ----------------
// idx < E: degree count.  idx >= E: build wTx[l][n][k] (l=0..3, n=0..143, k=0..127):
//   n<128: W_l[k][n] (l==3 -> Wf);  n>=128: head weights of layer l-1 (l==0 -> 0)
__global__ void k_count_prep(const int* __restrict__ dst, int E,
                             const float* __restrict__ Wl, const float* __restrict__ Wf,
                             const float* __restrict__ Wc, const float* __restrict__ WR,
                             const float* __restrict__ Wt,
                             _Float16* __restrict__ wTx, int* __restrict__ deg){
  int idx = blockIdx.x*256 + threadIdx.x;
  if (idx < E){
    atomicAdd(&deg[dst[idx]], 1);
    return;
  }
  int t = idx - E;
  if (t >= 4*WCOLS*128) return;
  int l = t / (WCOLS*128);
  int rem = t - l*(WCOLS*128);
  int n = rem >> 7;
  int k = rem & 127;
  float v = 0.f;
  if (n < 128){
    const float* W = (l < 3) ? (Wl + (size_t)l*16384) : Wf;
    v = W[k*128 + n];
  } else if (l > 0){
    int h = n - 128, hl = l - 1;
    if (h == 0)       v = Wc[(size_t)hl*128 + k];
    else if (h < 10)  v = WR[(size_t)hl*128*9 + k*9 + (h-1)];
    else if (h < 13)  v = Wt[(size_t)hl*128*3 + k*3 + (h-10)];
  }
  wTx[t] = (_Float16)v;
}

// ---------------- segment allocation: block scan + one global atomic ----------------
// sd[i] = {start, padded_degree}; cursor[i] = start. Order across blocks is arbitrary.
__global__ void k_alloc(const int* __restrict__ deg, int N, int2* __restrict__ sd,
                        int* __restrict__ cursor, int* __restrict__ gtot){
  __shared__ int s[256];
  __shared__ int sbase;
  int tid = threadIdx.x;
  int i = blockIdx.x*256 + tid;
  int d = (i < N) ? deg[i] : 0;
  int dp = (d + 7) & ~7;
  s[tid] = dp;
  __syncthreads();
#pragma unroll
  for (int off = 1; off < 256; off <<= 1){
    int add = (tid >= off) ? s[tid - off] : 0;
    __syncthreads();
    s[tid] += add;
    __syncthreads();
  }
  if (tid == 255) sbase = atomicAdd(gtot, s[255]);
  __syncthreads();
  int start = sbase + s[tid] - dp;
  if (i < N){
    sd[i] = make_int2(start, dp);
    cursor[i] = start;
  }
}

// ---------------- fill + tail pad (dummy index N) ----------------
__global__ void k_fillpad(const int* __restrict__ src, const int* __restrict__ dst,
                          int E, int N, int* __restrict__ cursor, int* __restrict__ csr,
                          const int2* __restrict__ sd, const int* __restrict__ deg){
  int idx = blockIdx.x*256 + threadIdx.x;
  if (idx < E){
    int p = atomicAdd(&cursor[dst[idx]], 1);
    csr[p] = src[idx];
  } else {
    int i = idx - E;
    if (i < N){
      int2 s = sd[i];
      int p = s.x + deg[i], pe = s.x + s.y;
      for (; p < pe; p++) csr[p] = N;
    }
  }
}

// ---------------- fp16 MFMA GEMM, 144 cols: H/z (cols 0-127) + head dots (128-140) ----------------
// 64 rows/block; waves 0,1: col-tiles 0-3; waves 2,3: col-tiles 4-8.
__launch_bounds__(256)
__global__ void k_gemm_mfma(const void* __restrict__ Xin, const _Float16* __restrict__ Wt,
                            const float* __restrict__ bias, void* __restrict__ Hout,
                            float* __restrict__ dsws,
                            int M, int in_fp32, int out_fp32, int zero_pad){
  const int wave = threadIdx.x >> 6;
  const int lane = threadIdx.x & 63;
  const int quad = lane >> 4;
  const int l16  = lane & 15;
  const int rbase = blockIdx.x*64 + (wave & 1)*32;
  const int ctb = (wave >> 1)*4;
  const int nct = (wave >> 1) ? 5 : 4;

  const _Float16* X16 = (const _Float16*)Xin;
  const float*    X32 = (const float*)Xin;

  floatx4 acc[2][5] = {};
#pragma unroll
  for (int kc = 0; kc < 4; kc++){
    half8 af[2];
#pragma unroll
    for (int rt = 0; rt < 2; rt++){
      int r = rbase + rt*16 + l16;
      r = (r < M) ? r : (M - 1);
      if (in_fp32){
        const float* p = X32 + (size_t)r*128 + kc*32 + quad*8;
        float4 f0 = *(const float4*)p;
        float4 f1 = *(const float4*)(p + 4);
        half8 a;
        a[0]=(_Float16)f0.x; a[1]=(_Float16)f0.y; a[2]=(_Float16)f0.z; a[3]=(_Float16)f0.w;
        a[4]=(_Float16)f1.x; a[5]=(_Float16)f1.y; a[6]=(_Float16)f1.z; a[7]=(_Float16)f1.w;
        af[rt] = a;
      } else {
        af[rt] = *(const half8*)(X16 + (size_t)r*128 + kc*32 + quad*8);
      }
    }
    for (int ct = 0; ct < nct; ct++){
      half8 bf = *(const half8*)(Wt + (size_t)((ctb+ct)*16 + l16)*128 + kc*32 + quad*8);
      acc[0][ct] = __builtin_amdgcn_mfma_f32_16x16x32_f16(af[0], bf, acc[0][ct], 0, 0, 0);
      acc[1][ct] = __builtin_amdgcn_mfma_f32_16x16x32_f16(af[1], bf, acc[1][ct], 0, 0, 0);
    }
  }
#pragma unroll
  for (int rt = 0; rt < 2; rt++){
    for (int ct = 0; ct < nct; ct++){
      int col = (ctb+ct)*16 + l16;
      float bv = (col < 128) ? bias[col] : 0.f;
#pragma unroll
      for (int reg = 0; reg < 4; reg++){
        int r = rbase + rt*16 + quad*4 + reg;
        if (r < M){
          float v = acc[rt][ct][reg] + bv;
          if (col < 128){
            if (out_fp32) ((float*)Hout)[(size_t)r*128 + col] = v;
            else          ((_Float16*)Hout)[(size_t)r*128 + col] = (_Float16)v;
          } else if (col < 141){
            dsws[(size_t)(col-128)*M + r] = v;
          }
        } else if (zero_pad && r == M && !out_fp32 && col < 128){
          ((_Float16*)Hout)[(size_t)r*128 + col] = (_Float16)0.f;
        }
      }
    }
  }
}

// ---------------- minimal gather-sum (+ fused se3 for previous layer) ----------------
__launch_bounds__(256)
__global__ void k_agg(const _Float16* __restrict__ H, const int* __restrict__ csr,
                      const int2* __restrict__ sd, _Float16* __restrict__ Xout,
                      int N, int agg_blocks,
                      const float* __restrict__ dsws, const float* __restrict__ bc,
                      const float* __restrict__ bR, const float* __restrict__ bt,
                      const float* __restrict__ pos_in, float* __restrict__ pos_o,
                      float* __restrict__ R_o, float* __restrict__ t_o, int se3_layer){
  if ((int)blockIdx.x >= agg_blocks){
    int n = (blockIdx.x - agg_blocks)*256 + threadIdx.x;
    if (n < N) se3_node(n, dsws, bc, bR, bt, pos_in, pos_o, R_o, t_o, se3_layer, N);
    return;
  }
  const int wave = threadIdx.x >> 6;
  const int lane = threadIdx.x & 63;
  const int node = blockIdx.x*4 + wave;
  if (node >= N) return;
  int2 s = sd[node];
  const int s0 = s.x, degp = s.y;
  const unsigned int* Hu = (const unsigned int*)H;   // half2/uint; row = 64 uints
  float acc0 = 0.f, acc1 = 0.f;
  for (int base = 0; base < degp; base += 64){
    int myidx = csr[s0 + base + lane];               // one coalesced load covers 64 edges
    int m = degp - base; m = (m < 64) ? m : 64;      // multiple of 8
    for (int k = 0; k < m; k += 8){
      unsigned int v[8];
#pragma unroll
      for (int j = 0; j < 8; j++){
        int idx = __builtin_amdgcn_readlane(myidx, k + j);   // SGPR row index
        v[j] = Hu[(size_t)idx*64 + lane];
      }
#pragma unroll
      for (int j = 0; j < 8; j++){
        float2 f = __half22float2(*(__half2*)&v[j]);
        acc0 += f.x; acc1 += f.y;
      }
    }
  }
  __half2 ho = __floats2half2_rn(acc0, acc1);
  ((unsigned int*)Xout)[(size_t)node*64 + lane] = *(unsigned int*)&ho;
}

// ---------------- standalone se3 (final layer) ----------------
__launch_bounds__(256)
__global__ void k_se3(const float* __restrict__ dsws,
                      const float* __restrict__ bc, const float* __restrict__ bR,
                      const float* __restrict__ bt, const float* __restrict__ pos_in,
                      float* __restrict__ pos_o, float* __restrict__ R_o, float* __restrict__ t_o,
                      int layer, int N){
  int n = blockIdx.x*256 + threadIdx.x;
  if (n < N) se3_node(n, dsws, bc, bR, bt, pos_in, pos_o, R_o, t_o, layer, N);
}

extern "C" void kernel_launch(void* const* d_in, const int* in_sizes, int n_in,
                              void* d_out, int out_size, void* d_ws, size_t ws_size,
                              hipStream_t stream){
  const float* x0  = (const float*)d_in[0];
  const float* pos = (const float*)d_in[1];
  const int*   ei  = (const int*)d_in[2];
  const float* Wl  = (const float*)d_in[3];
  const float* bl  = (const float*)d_in[4];
  const float* Wc  = (const float*)d_in[5];
  const float* bc  = (const float*)d_in[6];
  const float* WR  = (const float*)d_in[7];
  const float* bR  = (const float*)d_in[8];
  const float* Wt  = (const float*)d_in[9];
  const float* bt  = (const float*)d_in[10];
  const float* Wf  = (const float*)d_in[11];
  const float* bf  = (const float*)d_in[12];

  const int N = in_sizes[0] / 128;
  const int E = in_sizes[2] / 2;
  const int* srcp = ei;
  const int* dstp = ei + E;

  float* z_out = (float*)d_out;
  float* pos_o = z_out + (size_t)N*128;
  float* R_o   = pos_o + (size_t)N*3;
  float* t_o   = R_o   + (size_t)N*9;

  char* ws = (char*)d_ws;
  size_t off = 0;
  auto alloc = [&](size_t bytes)->char*{
    char* p = ws + off; off += (bytes + 511) & ~(size_t)511; return p;
  };
  _Float16* buf0h = (_Float16*)alloc((size_t)N*128*2);        // out16 ping
  _Float16* buf1h = (_Float16*)alloc((size_t)(N+1)*128*2);    // h16 (+dummy zero row N)
  _Float16* wTx   = (_Float16*)alloc((size_t)4*WCOLS*128*2);
  float* dsws  = (float*)alloc((size_t)13*N*4);
  int2* sd     = (int2*)alloc((size_t)N*8);
  int*  cursor = (int*) alloc((size_t)N*4);
  int*  deg    = (int*) alloc((size_t)(N+1)*4);               // deg[N] + gtot
  int*  csr    = (int*) alloc((size_t)(E + 7*(size_t)N + 128)*4);

  hipMemsetAsync(deg, 0, (size_t)(N+1)*4, stream);            // deg + gtot

  const int cp_total = E + 4*WCOLS*128;
  k_count_prep<<<dim3((cp_total+255)/256), dim3(256), 0, stream>>>(
      dstp, E, Wl, Wf, Wc, WR, Wt, wTx, deg);
  k_alloc<<<dim3((N+255)/256), dim3(256), 0, stream>>>(deg, N, sd, cursor, deg + N);
  k_fillpad<<<dim3((E+N+255)/256), dim3(256), 0, stream>>>(srcp, dstp, E, N, cursor, csr, sd, deg);

  const int gemm_blocks_pad = (N + 64)/64;    // covers dummy row N
  const int gemm_blocks     = (N + 63)/64;
  const int agg_blocks      = (N + 3)/4;
  const int se3_blocks      = (N + 255)/256;

  const void* xcur = (const void*)x0;
  for (int layer = 0; layer < 3; layer++){
    // GEMM layer `layer`; also computes head dots of layer-1 (dummy zeros for layer 0)
    k_gemm_mfma<<<dim3(gemm_blocks_pad), dim3(256), 0, stream>>>(
        xcur, wTx + (size_t)layer*WCOLS*128, bl + (size_t)layer*128, (void*)buf1h,
        dsws, N, (layer == 0) ? 1 : 0, 0, 1);
    // aggregation; extra blocks run se3 for layer-1 (heads written by this layer's GEMM)
    int extra = (layer >= 1) ? se3_blocks : 0;
    k_agg<<<dim3(agg_blocks + extra), dim3(256), 0, stream>>>(
        buf1h, csr, sd, buf0h, N, agg_blocks,
        dsws, bc + (layer-1), bR + (size_t)(layer-1)*9, bt + (size_t)(layer-1)*3,
        pos, pos_o, R_o, t_o, layer - 1);
    xcur = (const void*)buf0h;
  }
  // final GEMM (z) + head dots of layer 2
  k_gemm_mfma<<<dim3(gemm_blocks), dim3(256), 0, stream>>>(
      xcur, wTx + (size_t)3*WCOLS*128, bf, (void*)z_out, dsws, N, 0, 1, 0);
  k_se3<<<dim3(se3_blocks), dim3(256), 0, stream>>>(
      dsws, bc + 2, bR + 18, bt + 6, pos, pos_o, R_o, t_o, 2, N);
}

// Round 6
// 374.703 us; speedup vs baseline: 1.4801x; 1.4801x over previous
//
#include <hip/hip_runtime.h>
#include <hip/hip_fp16.h>

typedef _Float16 half8 __attribute__((ext_vector_type(8)));
typedef float floatx4 __attribute__((ext_vector_type(4)));

#define NHC 16            // head-col block (13 used + 3 pad)
#define WCOLS (128 + NHC) // 144 columns in extended W

// ---------------- QR: 3x3 Householder, LAPACK sgeqrf/sorgqr convention ----------------
__device__ inline void qr3_q(const double A[3][3], double Q[3][3]){
  double a[3][3];
#pragma unroll
  for (int r = 0; r < 3; r++)
#pragma unroll
    for (int c = 0; c < 3; c++) a[r][c] = A[r][c];

  double v1[3] = {1.0, 0.0, 0.0};
  double tau1 = 0.0;
  {
    double xn2 = a[1][0]*a[1][0] + a[2][0]*a[2][0];
    if (xn2 != 0.0){
      double alpha = a[0][0];
      double beta = -copysign(sqrt(alpha*alpha + xn2), alpha);
      tau1 = (beta - alpha) / beta;
      double inv = 1.0 / (alpha - beta);
      v1[1] = a[1][0] * inv;
      v1[2] = a[2][0] * inv;
#pragma unroll
      for (int c = 1; c < 3; c++){
        double w = a[0][c] + v1[1]*a[1][c] + v1[2]*a[2][c];
        double tw = tau1 * w;
        a[0][c] -= tw;
        a[1][c] -= tw * v1[1];
        a[2][c] -= tw * v1[2];
      }
    }
  }
  double tau2 = 0.0, v2 = 0.0;
  {
    double x2 = a[2][1];
    if (x2 != 0.0){
      double alpha = a[1][1];
      double beta = -copysign(sqrt(alpha*alpha + x2*x2), alpha);
      tau2 = (beta - alpha) / beta;
      v2 = x2 / (alpha - beta);
    }
  }
  double M[3][3] = {{1.0, 0.0, 0.0},
                    {0.0, 1.0 - tau2, -tau2*v2},
                    {0.0, -tau2*v2, 1.0 - tau2*v2*v2}};
#pragma unroll
  for (int c = 0; c < 3; c++){
    double w = v1[0]*M[0][c] + v1[1]*M[1][c] + v1[2]*M[2][c];
#pragma unroll
    for (int r = 0; r < 3; r++)
      Q[r][c] = M[r][c] - tau1 * v1[r] * w;
  }
}

// ---------------- SE(3) per-node epilogue (shared device body) ----------------
__device__ inline void se3_node(int n, const float* __restrict__ dsws,
                                const float* __restrict__ bc, const float* __restrict__ bR,
                                const float* __restrict__ bt, const float* __restrict__ pos_in,
                                float* __restrict__ pos_o, float* __restrict__ R_o,
                                float* __restrict__ t_o, int layer, int N){
  float ds[13];
#pragma unroll
  for (int c = 0; c < 13; c++) ds[c] = dsws[(size_t)c*N + n];

  double A[3][3], Q[3][3];
#pragma unroll
  for (int r = 0; r < 3; r++)
#pragma unroll
    for (int c = 0; c < 3; c++)
      A[r][c] = (double)ds[1 + r*3 + c] + (double)bR[r*3 + c];
  qr3_q(A, Q);

  double pd = (double)ds[0] + (double)bc[0];
#pragma unroll
  for (int c = 0; c < 3; c++){
    double base = (layer == 0) ? (double)pos_in[n*3 + c] : (double)pos_o[n*3 + c];
    pos_o[n*3 + c] = (float)(base + pd);
  }

  if (layer == 0){
#pragma unroll
    for (int r = 0; r < 3; r++)
#pragma unroll
      for (int c = 0; c < 3; c++)
        R_o[n*9 + r*3 + c] = (float)Q[r][c];
  } else {
    double Rold[3][3];
#pragma unroll
    for (int r = 0; r < 3; r++)
#pragma unroll
      for (int c = 0; c < 3; c++)
        Rold[r][c] = (double)R_o[n*9 + r*3 + c];
#pragma unroll
    for (int r = 0; r < 3; r++)
#pragma unroll
      for (int c = 0; c < 3; c++){
        double s = Q[r][0]*Rold[0][c] + Q[r][1]*Rold[1][c] + Q[r][2]*Rold[2][c];
        R_o[n*9 + r*3 + c] = (float)s;
      }
  }
#pragma unroll
  for (int c = 0; c < 3; c++){
    double base = (layer == 0) ? 0.0 : (double)t_o[n*3 + c];
    t_o[n*3 + c] = (float)(base + (double)ds[10 + c] + (double)bt[c]);
  }
}

// ---------------- fused count + weight prep ----------------
__global__ void k_count_prep(const int* __restrict__ dst, int E,
                             const float* __restrict__ Wl, const float* __restrict__ Wf,
                             const float* __restrict__ Wc, const float* __restrict__ WR,
                             const float* __restrict__ Wt,
                             _Float16* __restrict__ wTx, int* __restrict__ deg){
  int idx = blockIdx.x*256 + threadIdx.x;
  if (idx < E){
    atomicAdd(&deg[dst[idx]], 1);
    return;
  }
  int t = idx - E;
  if (t >= 4*WCOLS*128) return;
  int l = t / (WCOLS*128);
  int rem = t - l*(WCOLS*128);
  int n = rem >> 7;
  int k = rem & 127;
  float v = 0.f;
  if (n < 128){
    const float* W = (l < 3) ? (Wl + (size_t)l*16384) : Wf;
    v = W[k*128 + n];
  } else if (l > 0){
    int h = n - 128, hl = l - 1;
    if (h == 0)       v = Wc[(size_t)hl*128 + k];
    else if (h < 10)  v = WR[(size_t)hl*128*9 + k*9 + (h-1)];
    else if (h < 13)  v = Wt[(size_t)hl*128*3 + k*3 + (h-10)];
  }
  wTx[t] = (_Float16)v;
}

// ---------------- segment allocation: block scan + one global atomic ----------------
__global__ void k_alloc(const int* __restrict__ deg, int N, int2* __restrict__ sd,
                        int* __restrict__ cursor, int* __restrict__ gtot){
  __shared__ int s[256];
  __shared__ int sbase;
  int tid = threadIdx.x;
  int i = blockIdx.x*256 + tid;
  int d = (i < N) ? deg[i] : 0;
  int dp = (d + 7) & ~7;
  s[tid] = dp;
  __syncthreads();
#pragma unroll
  for (int off = 1; off < 256; off <<= 1){
    int add = (tid >= off) ? s[tid - off] : 0;
    __syncthreads();
    s[tid] += add;
    __syncthreads();
  }
  if (tid == 255) sbase = atomicAdd(gtot, s[255]);
  __syncthreads();
  int start = sbase + s[tid] - dp;
  if (i < N){
    sd[i] = make_int2(start, dp);
    cursor[i] = start;
  }
}

// ---------------- fill + tail pad (dummy index N) ----------------
__global__ void k_fillpad(const int* __restrict__ src, const int* __restrict__ dst,
                          int E, int N, int* __restrict__ cursor, int* __restrict__ csr,
                          const int2* __restrict__ sd, const int* __restrict__ deg){
  int idx = blockIdx.x*256 + threadIdx.x;
  if (idx < E){
    int p = atomicAdd(&cursor[dst[idx]], 1);
    csr[p] = src[idx];
  } else {
    int i = idx - E;
    if (i < N){
      int2 s = sd[i];
      int p = s.x + deg[i], pe = s.x + s.y;
      for (; p < pe; p++) csr[p] = N;
    }
  }
}

// ---------------- fp16 MFMA GEMM, 144 cols: H/z (cols 0-127) + head dots (128-140) ----------------
// 64 rows/block; waves 0,1: col-tiles 0-3; waves 2,3: col-tiles 4-8.
// NOTE: ct loops are compile-time unrolled (constant acc indices) — a runtime
// trip count here demotes acc[][] to scratch (R5: VGPR=24, 156MB spill traffic).
__launch_bounds__(256)
__global__ void k_gemm_mfma(const void* __restrict__ Xin, const _Float16* __restrict__ Wt,
                            const float* __restrict__ bias, void* __restrict__ Hout,
                            float* __restrict__ dsws,
                            int M, int in_fp32, int out_fp32, int zero_pad){
  const int wave = threadIdx.x >> 6;
  const int lane = threadIdx.x & 63;
  const int quad = lane >> 4;
  const int l16  = lane & 15;
  const int rbase = blockIdx.x*64 + (wave & 1)*32;
  const int cthi = wave >> 1;          // 0: tiles 0-3, 1: tiles 4-8
  const int ctb = cthi*4;

  const _Float16* X16 = (const _Float16*)Xin;
  const float*    X32 = (const float*)Xin;

  floatx4 acc[2][5] = {};
#pragma unroll
  for (int kc = 0; kc < 4; kc++){
    half8 af[2];
#pragma unroll
    for (int rt = 0; rt < 2; rt++){
      int r = rbase + rt*16 + l16;
      r = (r < M) ? r : (M - 1);
      if (in_fp32){
        const float* p = X32 + (size_t)r*128 + kc*32 + quad*8;
        float4 f0 = *(const float4*)p;
        float4 f1 = *(const float4*)(p + 4);
        half8 a;
        a[0]=(_Float16)f0.x; a[1]=(_Float16)f0.y; a[2]=(_Float16)f0.z; a[3]=(_Float16)f0.w;
        a[4]=(_Float16)f1.x; a[5]=(_Float16)f1.y; a[6]=(_Float16)f1.z; a[7]=(_Float16)f1.w;
        af[rt] = a;
      } else {
        af[rt] = *(const half8*)(X16 + (size_t)r*128 + kc*32 + quad*8);
      }
    }
#pragma unroll
    for (int ct = 0; ct < 5; ct++){
      if (ct == 4 && cthi == 0) continue;     // wave-uniform skip; indices stay constant
      half8 bf = *(const half8*)(Wt + (size_t)((ctb+ct)*16 + l16)*128 + kc*32 + quad*8);
      acc[0][ct] = __builtin_amdgcn_mfma_f32_16x16x32_f16(af[0], bf, acc[0][ct], 0, 0, 0);
      acc[1][ct] = __builtin_amdgcn_mfma_f32_16x16x32_f16(af[1], bf, acc[1][ct], 0, 0, 0);
    }
  }
#pragma unroll
  for (int rt = 0; rt < 2; rt++){
#pragma unroll
    for (int ct = 0; ct < 5; ct++){
      if (ct == 4 && cthi == 0) continue;
      int col = (ctb+ct)*16 + l16;
      float bv = (col < 128) ? bias[col] : 0.f;
#pragma unroll
      for (int reg = 0; reg < 4; reg++){
        int r = rbase + rt*16 + quad*4 + reg;
        if (r < M){
          float v = acc[rt][ct][reg] + bv;
          if (col < 128){
            if (out_fp32) ((float*)Hout)[(size_t)r*128 + col] = v;
            else          ((_Float16*)Hout)[(size_t)r*128 + col] = (_Float16)v;
          } else if (col < 141){
            dsws[(size_t)(col-128)*M + r] = v;
          }
        } else if (zero_pad && r == M && !out_fp32 && col < 128){
          ((_Float16*)Hout)[(size_t)r*128 + col] = (_Float16)0.f;
        }
      }
    }
  }
}

// ---------------- minimal gather-sum (+ fused se3 for previous layer) ----------------
__launch_bounds__(256)
__global__ void k_agg(const _Float16* __restrict__ H, const int* __restrict__ csr,
                      const int2* __restrict__ sd, _Float16* __restrict__ Xout,
                      int N, int agg_blocks,
                      const float* __restrict__ dsws, const float* __restrict__ bc,
                      const float* __restrict__ bR, const float* __restrict__ bt,
                      const float* __restrict__ pos_in, float* __restrict__ pos_o,
                      float* __restrict__ R_o, float* __restrict__ t_o, int se3_layer){
  if ((int)blockIdx.x >= agg_blocks){
    int n = (blockIdx.x - agg_blocks)*256 + threadIdx.x;
    if (n < N) se3_node(n, dsws, bc, bR, bt, pos_in, pos_o, R_o, t_o, se3_layer, N);
    return;
  }
  const int wave = threadIdx.x >> 6;
  const int lane = threadIdx.x & 63;
  const int node = blockIdx.x*4 + wave;
  if (node >= N) return;
  int2 s = sd[node];
  const int s0 = s.x, degp = s.y;
  const unsigned int* Hu = (const unsigned int*)H;   // half2/uint; row = 64 uints
  float acc0 = 0.f, acc1 = 0.f;
  for (int base = 0; base < degp; base += 64){
    int myidx = csr[s0 + base + lane];               // one coalesced load covers 64 edges
    int m = degp - base; m = (m < 64) ? m : 64;      // multiple of 8
    for (int k = 0; k < m; k += 8){
      unsigned int v[8];
#pragma unroll
      for (int j = 0; j < 8; j++){
        int idx = __builtin_amdgcn_readlane(myidx, k + j);   // SGPR row index
        v[j] = Hu[(size_t)idx*64 + lane];
      }
#pragma unroll
      for (int j = 0; j < 8; j++){
        float2 f = __half22float2(*(__half2*)&v[j]);
        acc0 += f.x; acc1 += f.y;
      }
    }
  }
  __half2 ho = __floats2half2_rn(acc0, acc1);
  ((unsigned int*)Xout)[(size_t)node*64 + lane] = *(unsigned int*)&ho;
}

// ---------------- standalone se3 (final layer) ----------------
__launch_bounds__(256)
__global__ void k_se3(const float* __restrict__ dsws,
                      const float* __restrict__ bc, const float* __restrict__ bR,
                      const float* __restrict__ bt, const float* __restrict__ pos_in,
                      float* __restrict__ pos_o, float* __restrict__ R_o, float* __restrict__ t_o,
                      int layer, int N){
  int n = blockIdx.x*256 + threadIdx.x;
  if (n < N) se3_node(n, dsws, bc, bR, bt, pos_in, pos_o, R_o, t_o, layer, N);
}

extern "C" void kernel_launch(void* const* d_in, const int* in_sizes, int n_in,
                              void* d_out, int out_size, void* d_ws, size_t ws_size,
                              hipStream_t stream){
  const float* x0  = (const float*)d_in[0];
  const float* pos = (const float*)d_in[1];
  const int*   ei  = (const int*)d_in[2];
  const float* Wl  = (const float*)d_in[3];
  const float* bl  = (const float*)d_in[4];
  const float* Wc  = (const float*)d_in[5];
  const float* bc  = (const float*)d_in[6];
  const float* WR  = (const float*)d_in[7];
  const float* bR  = (const float*)d_in[8];
  const float* Wt  = (const float*)d_in[9];
  const float* bt  = (const float*)d_in[10];
  const float* Wf  = (const float*)d_in[11];
  const float* bf  = (const float*)d_in[12];

  const int N = in_sizes[0] / 128;
  const int E = in_sizes[2] / 2;
  const int* srcp = ei;
  const int* dstp = ei + E;

  float* z_out = (float*)d_out;
  float* pos_o = z_out + (size_t)N*128;
  float* R_o   = pos_o + (size_t)N*3;
  float* t_o   = R_o   + (size_t)N*9;

  char* ws = (char*)d_ws;
  size_t off = 0;
  auto alloc = [&](size_t bytes)->char*{
    char* p = ws + off; off += (bytes + 511) & ~(size_t)511; return p;
  };
  _Float16* buf0h = (_Float16*)alloc((size_t)N*128*2);        // out16 ping
  _Float16* buf1h = (_Float16*)alloc((size_t)(N+1)*128*2);    // h16 (+dummy zero row N)
  _Float16* wTx   = (_Float16*)alloc((size_t)4*WCOLS*128*2);
  float* dsws  = (float*)alloc((size_t)13*N*4);
  int2* sd     = (int2*)alloc((size_t)N*8);
  int*  cursor = (int*) alloc((size_t)N*4);
  int*  deg    = (int*) alloc((size_t)(N+1)*4);               // deg[N] + gtot
  int*  csr    = (int*) alloc((size_t)(E + 7*(size_t)N + 128)*4);

  hipMemsetAsync(deg, 0, (size_t)(N+1)*4, stream);            // deg + gtot

  const int cp_total = E + 4*WCOLS*128;
  k_count_prep<<<dim3((cp_total+255)/256), dim3(256), 0, stream>>>(
      dstp, E, Wl, Wf, Wc, WR, Wt, wTx, deg);
  k_alloc<<<dim3((N+255)/256), dim3(256), 0, stream>>>(deg, N, sd, cursor, deg + N);
  k_fillpad<<<dim3((E+N+255)/256), dim3(256), 0, stream>>>(srcp, dstp, E, N, cursor, csr, sd, deg);

  const int gemm_blocks_pad = (N + 64)/64;    // covers dummy row N
  const int gemm_blocks     = (N + 63)/64;
  const int agg_blocks      = (N + 3)/4;
  const int se3_blocks      = (N + 255)/256;

  const void* xcur = (const void*)x0;
  for (int layer = 0; layer < 3; layer++){
    k_gemm_mfma<<<dim3(gemm_blocks_pad), dim3(256), 0, stream>>>(
        xcur, wTx + (size_t)layer*WCOLS*128, bl + (size_t)layer*128, (void*)buf1h,
        dsws, N, (layer == 0) ? 1 : 0, 0, 1);
    int extra = (layer >= 1) ? se3_blocks : 0;
    k_agg<<<dim3(agg_blocks + extra), dim3(256), 0, stream>>>(
        buf1h, csr, sd, buf0h, N, agg_blocks,
        dsws, bc + (layer-1), bR + (size_t)(layer-1)*9, bt + (size_t)(layer-1)*3,
        pos, pos_o, R_o, t_o, layer - 1);
    xcur = (const void*)buf0h;
  }
  k_gemm_mfma<<<dim3(gemm_blocks), dim3(256), 0, stream>>>(
      xcur, wTx + (size_t)3*WCOLS*128, bf, (void*)z_out, dsws, N, 0, 1, 0);
  k_se3<<<dim3(se3_blocks), dim3(256), 0, stream>>>(
      dsws, bc + 2, bR + 18, bt + 6, pos, pos_o, R_o, t_o, 2, N);
}

// Round 7
// 323.546 us; speedup vs baseline: 1.7142x; 1.1581x over previous
//
#include <hip/hip_runtime.h>
#include <hip/hip_fp16.h>

typedef _Float16 half8 __attribute__((ext_vector_type(8)));
typedef float floatx4 __attribute__((ext_vector_type(4)));

#define NHC 16            // head-col block (13 used + 3 pad)
#define WCOLS (128 + NHC) // 144 columns in extended W
// bucket = 512 consecutive dst nodes; assumes N <= 65536 (src fits 23 bits in pack)

// ---------------- QR: 3x3 Householder, LAPACK sgeqrf/sorgqr convention ----------------
__device__ inline void qr3_q(const double A[3][3], double Q[3][3]){
  double a[3][3];
#pragma unroll
  for (int r = 0; r < 3; r++)
#pragma unroll
    for (int c = 0; c < 3; c++) a[r][c] = A[r][c];

  double v1[3] = {1.0, 0.0, 0.0};
  double tau1 = 0.0;
  {
    double xn2 = a[1][0]*a[1][0] + a[2][0]*a[2][0];
    if (xn2 != 0.0){
      double alpha = a[0][0];
      double beta = -copysign(sqrt(alpha*alpha + xn2), alpha);
      tau1 = (beta - alpha) / beta;
      double inv = 1.0 / (alpha - beta);
      v1[1] = a[1][0] * inv;
      v1[2] = a[2][0] * inv;
#pragma unroll
      for (int c = 1; c < 3; c++){
        double w = a[0][c] + v1[1]*a[1][c] + v1[2]*a[2][c];
        double tw = tau1 * w;
        a[0][c] -= tw;
        a[1][c] -= tw * v1[1];
        a[2][c] -= tw * v1[2];
      }
    }
  }
  double tau2 = 0.0, v2 = 0.0;
  {
    double x2 = a[2][1];
    if (x2 != 0.0){
      double alpha = a[1][1];
      double beta = -copysign(sqrt(alpha*alpha + x2*x2), alpha);
      tau2 = (beta - alpha) / beta;
      v2 = x2 / (alpha - beta);
    }
  }
  double M[3][3] = {{1.0, 0.0, 0.0},
                    {0.0, 1.0 - tau2, -tau2*v2},
                    {0.0, -tau2*v2, 1.0 - tau2*v2*v2}};
#pragma unroll
  for (int c = 0; c < 3; c++){
    double w = v1[0]*M[0][c] + v1[1]*M[1][c] + v1[2]*M[2][c];
#pragma unroll
    for (int r = 0; r < 3; r++)
      Q[r][c] = M[r][c] - tau1 * v1[r] * w;
  }
}

// ---------------- SE(3) per-node epilogue (shared device body) ----------------
__device__ inline void se3_node(int n, const float* __restrict__ dsws,
                                const float* __restrict__ bc, const float* __restrict__ bR,
                                const float* __restrict__ bt, const float* __restrict__ pos_in,
                                float* __restrict__ pos_o, float* __restrict__ R_o,
                                float* __restrict__ t_o, int layer, int N){
  float ds[13];
#pragma unroll
  for (int c = 0; c < 13; c++) ds[c] = dsws[(size_t)c*N + n];

  double A[3][3], Q[3][3];
#pragma unroll
  for (int r = 0; r < 3; r++)
#pragma unroll
    for (int c = 0; c < 3; c++)
      A[r][c] = (double)ds[1 + r*3 + c] + (double)bR[r*3 + c];
  qr3_q(A, Q);

  double pd = (double)ds[0] + (double)bc[0];
#pragma unroll
  for (int c = 0; c < 3; c++){
    double base = (layer == 0) ? (double)pos_in[n*3 + c] : (double)pos_o[n*3 + c];
    pos_o[n*3 + c] = (float)(base + pd);
  }

  if (layer == 0){
#pragma unroll
    for (int r = 0; r < 3; r++)
#pragma unroll
      for (int c = 0; c < 3; c++)
        R_o[n*9 + r*3 + c] = (float)Q[r][c];
  } else {
    double Rold[3][3];
#pragma unroll
    for (int r = 0; r < 3; r++)
#pragma unroll
      for (int c = 0; c < 3; c++)
        Rold[r][c] = (double)R_o[n*9 + r*3 + c];
#pragma unroll
    for (int r = 0; r < 3; r++)
#pragma unroll
      for (int c = 0; c < 3; c++){
        double s = Q[r][0]*Rold[0][c] + Q[r][1]*Rold[1][c] + Q[r][2]*Rold[2][c];
        R_o[n*9 + r*3 + c] = (float)s;
      }
  }
#pragma unroll
  for (int c = 0; c < 3; c++){
    double base = (layer == 0) ? 0.0 : (double)t_o[n*3 + c];
    t_o[n*3 + c] = (float)(base + (double)ds[10 + c] + (double)bt[c]);
  }
}

// ---------------- weight prep: wTx[l][n][k] (l=0..3, n=0..143, k=0..127) ----------------
__global__ void k_prep_w(const float* __restrict__ Wl, const float* __restrict__ Wf,
                         const float* __restrict__ Wc, const float* __restrict__ WR,
                         const float* __restrict__ Wt, _Float16* __restrict__ wTx){
  int t = blockIdx.x*256 + threadIdx.x;
  if (t >= 4*WCOLS*128) return;
  int l = t / (WCOLS*128);
  int rem = t - l*(WCOLS*128);
  int n = rem >> 7;
  int k = rem & 127;
  float v = 0.f;
  if (n < 128){
    const float* W = (l < 3) ? (Wl + (size_t)l*16384) : Wf;
    v = W[k*128 + n];
  } else if (l > 0){
    int h = n - 128, hl = l - 1;
    if (h == 0)       v = Wc[(size_t)hl*128 + k];
    else if (h < 10)  v = WR[(size_t)hl*128*9 + k*9 + (h-1)];
    else if (h < 13)  v = Wt[(size_t)hl*128*3 + k*3 + (h-10)];
  }
  wTx[t] = (_Float16)v;
}

// ---------------- pass 1: bin edges into 512-node buckets (LDS count + segment write) ----
// 4096 edges per WG; ~19k global atomics total; segments single-WG-owned -> full-line WB.
__launch_bounds__(256)
__global__ void k_bin(const int* __restrict__ src, const int* __restrict__ dst,
                      int E, int nbuck, int capB,
                      int* __restrict__ cursor, int* __restrict__ binned){
  __shared__ int cnt[128];
  __shared__ int segbase[128];
  const int tid = threadIdx.x;
  for (int t = tid; t < nbuck; t += 256) cnt[t] = 0;
  __syncthreads();
  const int e0 = blockIdx.x*4096 + tid;
  int pk[16], bk[16];
#pragma unroll
  for (int j = 0; j < 16; j++){
    int e = e0 + j*256;
    if (e < E){
      int d = dst[e], s = src[e];
      bk[j] = d >> 9;
      pk[j] = (s << 9) | (d & 511);
      atomicAdd(&cnt[bk[j]], 1);
    } else bk[j] = -1;
  }
  __syncthreads();
  for (int t = tid; t < nbuck; t += 256){
    int c = cnt[t];
    if (c > 0) segbase[t] = t*capB + atomicAdd(&cursor[t], c);
    cnt[t] = 0;
  }
  __syncthreads();
#pragma unroll
  for (int j = 0; j < 16; j++){
    if (bk[j] >= 0){
      int ord = atomicAdd(&cnt[bk[j]], 1);
      binned[segbase[bk[j]] + ord] = pk[j];
    }
  }
}

// ---------------- pass 2: per-bucket exact CSR (LDS deg/scan/scatter, private region) ----
__launch_bounds__(256)
__global__ void k_build(const int* __restrict__ binned, const int* __restrict__ cursor,
                        int N, int capB, int capC,
                        int2* __restrict__ sd, int* __restrict__ csr){
  __shared__ int deg[512];
  __shared__ int lstart[512];
  __shared__ int cnt2[512];
  __shared__ int scn[256];
  const int b = blockIdx.x, tid = threadIdx.x;
  deg[tid] = 0; deg[tid+256] = 0;
  __syncthreads();
  const int nE = cursor[b];
  const int gbase = b*capB;
  for (int i = tid; i < nE; i += 256)
    atomicAdd(&deg[binned[gbase + i] & 511], 1);
  __syncthreads();
  const int d0 = deg[2*tid], d1 = deg[2*tid+1];
  const int p0 = (d0+7)&~7,  p1 = (d1+7)&~7;
  scn[tid] = p0 + p1;
  __syncthreads();
#pragma unroll
  for (int off = 1; off < 256; off <<= 1){
    int add = (tid >= off) ? scn[tid-off] : 0;
    __syncthreads();
    scn[tid] += add;
    __syncthreads();
  }
  const int ex = scn[tid] - (p0 + p1);
  const int csrb = b*capC;
  lstart[2*tid]   = ex;
  lstart[2*tid+1] = ex + p0;
  cnt2[2*tid] = 0; cnt2[2*tid+1] = 0;
  const int n0 = b*512 + 2*tid, n1 = n0 + 1;
  if (n0 < N) sd[n0] = make_int2(csrb + ex, p0);
  if (n1 < N) sd[n1] = make_int2(csrb + ex + p0, p1);
  __syncthreads();
  for (int i = tid; i < nE; i += 256){
    int v = binned[gbase + i];
    int dl = v & 511, s = v >> 9;
    int ord = atomicAdd(&cnt2[dl], 1);
    csr[csrb + lstart[dl] + ord] = s;
  }
  for (int j = d0; j < p0; j++) csr[csrb + lstart[2*tid]   + j] = N;
  for (int j = d1; j < p1; j++) csr[csrb + lstart[2*tid+1] + j] = N;
}

// ---------------- fp16 MFMA GEMM, 144 cols: H/z (cols 0-127) + head dots (128-140) ----------------
// 64 rows/block; waves 0,1: col-tiles 0-3; waves 2,3: col-tiles 4-8.
// NOTE: ct loops are compile-time unrolled (constant acc indices) — a runtime
// trip count here demotes acc[][] to scratch (R5: VGPR=24, 156MB spill traffic).
__launch_bounds__(256)
__global__ void k_gemm_mfma(const void* __restrict__ Xin, const _Float16* __restrict__ Wt,
                            const float* __restrict__ bias, void* __restrict__ Hout,
                            float* __restrict__ dsws,
                            int M, int in_fp32, int out_fp32, int zero_pad){
  const int wave = threadIdx.x >> 6;
  const int lane = threadIdx.x & 63;
  const int quad = lane >> 4;
  const int l16  = lane & 15;
  const int rbase = blockIdx.x*64 + (wave & 1)*32;
  const int cthi = wave >> 1;          // 0: tiles 0-3, 1: tiles 4-8
  const int ctb = cthi*4;

  const _Float16* X16 = (const _Float16*)Xin;
  const float*    X32 = (const float*)Xin;

  floatx4 acc[2][5] = {};
#pragma unroll
  for (int kc = 0; kc < 4; kc++){
    half8 af[2];
#pragma unroll
    for (int rt = 0; rt < 2; rt++){
      int r = rbase + rt*16 + l16;
      r = (r < M) ? r : (M - 1);
      if (in_fp32){
        const float* p = X32 + (size_t)r*128 + kc*32 + quad*8;
        float4 f0 = *(const float4*)p;
        float4 f1 = *(const float4*)(p + 4);
        half8 a;
        a[0]=(_Float16)f0.x; a[1]=(_Float16)f0.y; a[2]=(_Float16)f0.z; a[3]=(_Float16)f0.w;
        a[4]=(_Float16)f1.x; a[5]=(_Float16)f1.y; a[6]=(_Float16)f1.z; a[7]=(_Float16)f1.w;
        af[rt] = a;
      } else {
        af[rt] = *(const half8*)(X16 + (size_t)r*128 + kc*32 + quad*8);
      }
    }
#pragma unroll
    for (int ct = 0; ct < 5; ct++){
      if (ct == 4 && cthi == 0) continue;     // wave-uniform skip; indices stay constant
      half8 bf = *(const half8*)(Wt + (size_t)((ctb+ct)*16 + l16)*128 + kc*32 + quad*8);
      acc[0][ct] = __builtin_amdgcn_mfma_f32_16x16x32_f16(af[0], bf, acc[0][ct], 0, 0, 0);
      acc[1][ct] = __builtin_amdgcn_mfma_f32_16x16x32_f16(af[1], bf, acc[1][ct], 0, 0, 0);
    }
  }
#pragma unroll
  for (int rt = 0; rt < 2; rt++){
#pragma unroll
    for (int ct = 0; ct < 5; ct++){
      if (ct == 4 && cthi == 0) continue;
      int col = (ctb+ct)*16 + l16;
      float bv = (col < 128) ? bias[col] : 0.f;
#pragma unroll
      for (int reg = 0; reg < 4; reg++){
        int r = rbase + rt*16 + quad*4 + reg;
        if (r < M){
          float v = acc[rt][ct][reg] + bv;
          if (col < 128){
            if (out_fp32) ((float*)Hout)[(size_t)r*128 + col] = v;
            else          ((_Float16*)Hout)[(size_t)r*128 + col] = (_Float16)v;
          } else if (col < 141){
            dsws[(size_t)(col-128)*M + r] = v;
          }
        } else if (zero_pad && r == M && !out_fp32 && col < 128){
          ((_Float16*)Hout)[(size_t)r*128 + col] = (_Float16)0.f;
        }
      }
    }
  }
}

// ---------------- minimal gather-sum (+ fused se3 for previous layer) ----------------
__launch_bounds__(256)
__global__ void k_agg(const _Float16* __restrict__ H, const int* __restrict__ csr,
                      const int2* __restrict__ sd, _Float16* __restrict__ Xout,
                      int N, int agg_blocks,
                      const float* __restrict__ dsws, const float* __restrict__ bc,
                      const float* __restrict__ bR, const float* __restrict__ bt,
                      const float* __restrict__ pos_in, float* __restrict__ pos_o,
                      float* __restrict__ R_o, float* __restrict__ t_o, int se3_layer){
  if ((int)blockIdx.x >= agg_blocks){
    int n = (blockIdx.x - agg_blocks)*256 + threadIdx.x;
    if (n < N) se3_node(n, dsws, bc, bR, bt, pos_in, pos_o, R_o, t_o, se3_layer, N);
    return;
  }
  const int wave = threadIdx.x >> 6;
  const int lane = threadIdx.x & 63;
  const int node = blockIdx.x*4 + wave;
  if (node >= N) return;
  int2 s = sd[node];
  const int s0 = s.x, degp = s.y;
  const unsigned int* Hu = (const unsigned int*)H;   // half2/uint; row = 64 uints
  float acc0 = 0.f, acc1 = 0.f;
  for (int base = 0; base < degp; base += 64){
    int myidx = csr[s0 + base + lane];               // one coalesced load covers 64 edges
    int m = degp - base; m = (m < 64) ? m : 64;      // multiple of 8
    for (int k = 0; k < m; k += 8){
      unsigned int v[8];
#pragma unroll
      for (int j = 0; j < 8; j++){
        int idx = __builtin_amdgcn_readlane(myidx, k + j);   // SGPR row index
        v[j] = Hu[(size_t)idx*64 + lane];
      }
#pragma unroll
      for (int j = 0; j < 8; j++){
        float2 f = __half22float2(*(__half2*)&v[j]);
        acc0 += f.x; acc1 += f.y;
      }
    }
  }
  __half2 ho = __floats2half2_rn(acc0, acc1);
  ((unsigned int*)Xout)[(size_t)node*64 + lane] = *(unsigned int*)&ho;
}

// ---------------- standalone se3 (final layer) ----------------
__launch_bounds__(256)
__global__ void k_se3(const float* __restrict__ dsws,
                      const float* __restrict__ bc, const float* __restrict__ bR,
                      const float* __restrict__ bt, const float* __restrict__ pos_in,
                      float* __restrict__ pos_o, float* __restrict__ R_o, float* __restrict__ t_o,
                      int layer, int N){
  int n = blockIdx.x*256 + threadIdx.x;
  if (n < N) se3_node(n, dsws, bc, bR, bt, pos_in, pos_o, R_o, t_o, layer, N);
}

extern "C" void kernel_launch(void* const* d_in, const int* in_sizes, int n_in,
                              void* d_out, int out_size, void* d_ws, size_t ws_size,
                              hipStream_t stream){
  const float* x0  = (const float*)d_in[0];
  const float* pos = (const float*)d_in[1];
  const int*   ei  = (const int*)d_in[2];
  const float* Wl  = (const float*)d_in[3];
  const float* bl  = (const float*)d_in[4];
  const float* Wc  = (const float*)d_in[5];
  const float* bc  = (const float*)d_in[6];
  const float* WR  = (const float*)d_in[7];
  const float* bR  = (const float*)d_in[8];
  const float* Wt  = (const float*)d_in[9];
  const float* bt  = (const float*)d_in[10];
  const float* Wf  = (const float*)d_in[11];
  const float* bf  = (const float*)d_in[12];

  const int N = in_sizes[0] / 128;
  const int E = in_sizes[2] / 2;
  const int* srcp = ei;
  const int* dstp = ei + E;

  float* z_out = (float*)d_out;
  float* pos_o = z_out + (size_t)N*128;
  float* R_o   = pos_o + (size_t)N*3;
  float* t_o   = R_o   + (size_t)N*9;

  const int nbuck = (N + 511) >> 9;                       // 512-node buckets (<=128)
  const int capB  = (((E + nbuck - 1)/nbuck)*5/4 + 256 + 63) & ~63;  // binned capacity/bucket
  const int capC  = capB + 512*7;                          // csr capacity/bucket (max padding)

  char* ws = (char*)d_ws;
  size_t off = 0;
  auto alloc = [&](size_t bytes)->char*{
    char* p = ws + off; off += (bytes + 511) & ~(size_t)511; return p;
  };
  _Float16* buf0h = (_Float16*)alloc((size_t)N*128*2);        // out16 ping
  _Float16* buf1h = (_Float16*)alloc((size_t)(N+1)*128*2);    // h16 (+dummy zero row N)
  _Float16* wTx   = (_Float16*)alloc((size_t)4*WCOLS*128*2);
  float* dsws   = (float*)alloc((size_t)13*N*4);
  int2*  sd     = (int2*) alloc((size_t)N*8);
  int*   cursor = (int*)  alloc((size_t)nbuck*4);
  int*   binned = (int*)  alloc((size_t)nbuck*capB*4);
  int*   csr    = (int*)  alloc((size_t)nbuck*capC*4);

  hipMemsetAsync(cursor, 0, (size_t)nbuck*4, stream);

  k_prep_w<<<dim3((4*WCOLS*128 + 255)/256), dim3(256), 0, stream>>>(Wl, Wf, Wc, WR, Wt, wTx);
  k_bin   <<<dim3((E + 4095)/4096), dim3(256), 0, stream>>>(srcp, dstp, E, nbuck, capB, cursor, binned);
  k_build <<<dim3(nbuck), dim3(256), 0, stream>>>(binned, cursor, N, capB, capC, sd, csr);

  const int gemm_blocks_pad = (N + 64)/64;    // covers dummy row N
  const int gemm_blocks     = (N + 63)/64;
  const int agg_blocks      = (N + 3)/4;
  const int se3_blocks      = (N + 255)/256;

  const void* xcur = (const void*)x0;
  for (int layer = 0; layer < 3; layer++){
    k_gemm_mfma<<<dim3(gemm_blocks_pad), dim3(256), 0, stream>>>(
        xcur, wTx + (size_t)layer*WCOLS*128, bl + (size_t)layer*128, (void*)buf1h,
        dsws, N, (layer == 0) ? 1 : 0, 0, 1);
    int extra = (layer >= 1) ? se3_blocks : 0;
    k_agg<<<dim3(agg_blocks + extra), dim3(256), 0, stream>>>(
        buf1h, csr, sd, buf0h, N, agg_blocks,
        dsws, bc + (layer-1), bR + (size_t)(layer-1)*9, bt + (size_t)(layer-1)*3,
        pos, pos_o, R_o, t_o, layer - 1);
    xcur = (const void*)buf0h;
  }
  k_gemm_mfma<<<dim3(gemm_blocks), dim3(256), 0, stream>>>(
      xcur, wTx + (size_t)3*WCOLS*128, bf, (void*)z_out, dsws, N, 0, 1, 0);
  k_se3<<<dim3(se3_blocks), dim3(256), 0, stream>>>(
      dsws, bc + 2, bR + 18, bt + 6, pos, pos_o, R_o, t_o, 2, N);
}

// Round 8
// 318.745 us; speedup vs baseline: 1.7400x; 1.0151x over previous
//
#include <hip/hip_runtime.h>
#include <hip/hip_fp16.h>

typedef _Float16 half8 __attribute__((ext_vector_type(8)));
typedef float floatx4 __attribute__((ext_vector_type(4)));

#define NHC 16            // head-col block (13 used + 3 pad)
#define WCOLS (128 + NHC) // 144 columns in extended W
#define OSH 13            // src-octile shift: 8192 rows = 2MB fp16 (fits per-XCD L2)
// bucket = 512 consecutive dst nodes; assumes N <= 65536 (src fits 23 bits in pack)

// ---------------- QR: 3x3 Householder, LAPACK sgeqrf/sorgqr convention ----------------
__device__ inline void qr3_q(const double A[3][3], double Q[3][3]){
  double a[3][3];
#pragma unroll
  for (int r = 0; r < 3; r++)
#pragma unroll
    for (int c = 0; c < 3; c++) a[r][c] = A[r][c];

  double v1[3] = {1.0, 0.0, 0.0};
  double tau1 = 0.0;
  {
    double xn2 = a[1][0]*a[1][0] + a[2][0]*a[2][0];
    if (xn2 != 0.0){
      double alpha = a[0][0];
      double beta = -copysign(sqrt(alpha*alpha + xn2), alpha);
      tau1 = (beta - alpha) / beta;
      double inv = 1.0 / (alpha - beta);
      v1[1] = a[1][0] * inv;
      v1[2] = a[2][0] * inv;
#pragma unroll
      for (int c = 1; c < 3; c++){
        double w = a[0][c] + v1[1]*a[1][c] + v1[2]*a[2][c];
        double tw = tau1 * w;
        a[0][c] -= tw;
        a[1][c] -= tw * v1[1];
        a[2][c] -= tw * v1[2];
      }
    }
  }
  double tau2 = 0.0, v2 = 0.0;
  {
    double x2 = a[2][1];
    if (x2 != 0.0){
      double alpha = a[1][1];
      double beta = -copysign(sqrt(alpha*alpha + x2*x2), alpha);
      tau2 = (beta - alpha) / beta;
      v2 = x2 / (alpha - beta);
    }
  }
  double M[3][3] = {{1.0, 0.0, 0.0},
                    {0.0, 1.0 - tau2, -tau2*v2},
                    {0.0, -tau2*v2, 1.0 - tau2*v2*v2}};
#pragma unroll
  for (int c = 0; c < 3; c++){
    double w = v1[0]*M[0][c] + v1[1]*M[1][c] + v1[2]*M[2][c];
#pragma unroll
    for (int r = 0; r < 3; r++)
      Q[r][c] = M[r][c] - tau1 * v1[r] * w;
  }
}

// ---------------- SE(3) per-node epilogue (shared device body) ----------------
__device__ inline void se3_node(int n, const float* __restrict__ dsws,
                                const float* __restrict__ bc, const float* __restrict__ bR,
                                const float* __restrict__ bt, const float* __restrict__ pos_in,
                                float* __restrict__ pos_o, float* __restrict__ R_o,
                                float* __restrict__ t_o, int layer, int N){
  float ds[13];
#pragma unroll
  for (int c = 0; c < 13; c++) ds[c] = dsws[(size_t)c*N + n];

  double A[3][3], Q[3][3];
#pragma unroll
  for (int r = 0; r < 3; r++)
#pragma unroll
    for (int c = 0; c < 3; c++)
      A[r][c] = (double)ds[1 + r*3 + c] + (double)bR[r*3 + c];
  qr3_q(A, Q);

  double pd = (double)ds[0] + (double)bc[0];
#pragma unroll
  for (int c = 0; c < 3; c++){
    double base = (layer == 0) ? (double)pos_in[n*3 + c] : (double)pos_o[n*3 + c];
    pos_o[n*3 + c] = (float)(base + pd);
  }

  if (layer == 0){
#pragma unroll
    for (int r = 0; r < 3; r++)
#pragma unroll
      for (int c = 0; c < 3; c++)
        R_o[n*9 + r*3 + c] = (float)Q[r][c];
  } else {
    double Rold[3][3];
#pragma unroll
    for (int r = 0; r < 3; r++)
#pragma unroll
      for (int c = 0; c < 3; c++)
        Rold[r][c] = (double)R_o[n*9 + r*3 + c];
#pragma unroll
    for (int r = 0; r < 3; r++)
#pragma unroll
      for (int c = 0; c < 3; c++){
        double s = Q[r][0]*Rold[0][c] + Q[r][1]*Rold[1][c] + Q[r][2]*Rold[2][c];
        R_o[n*9 + r*3 + c] = (float)s;
      }
  }
#pragma unroll
  for (int c = 0; c < 3; c++){
    double base = (layer == 0) ? 0.0 : (double)t_o[n*3 + c];
    t_o[n*3 + c] = (float)(base + (double)ds[10 + c] + (double)bt[c]);
  }
}

// ---------------- weight prep (+ cursor zero-init, fused) ----------------
__global__ void k_prep_w(const float* __restrict__ Wl, const float* __restrict__ Wf,
                         const float* __restrict__ Wc, const float* __restrict__ WR,
                         const float* __restrict__ Wt, _Float16* __restrict__ wTx,
                         int* __restrict__ cursor, int nbuck){
  int t = blockIdx.x*256 + threadIdx.x;
  if (blockIdx.x == 0 && threadIdx.x < nbuck) cursor[threadIdx.x] = 0;
  if (t >= 4*WCOLS*128) return;
  int l = t / (WCOLS*128);
  int rem = t - l*(WCOLS*128);
  int n = rem >> 7;
  int k = rem & 127;
  float v = 0.f;
  if (n < 128){
    const float* W = (l < 3) ? (Wl + (size_t)l*16384) : Wf;
    v = W[k*128 + n];
  } else if (l > 0){
    int h = n - 128, hl = l - 1;
    if (h == 0)       v = Wc[(size_t)hl*128 + k];
    else if (h < 10)  v = WR[(size_t)hl*128*9 + k*9 + (h-1)];
    else if (h < 13)  v = Wt[(size_t)hl*128*3 + k*3 + (h-10)];
  }
  wTx[t] = (_Float16)v;
}

// ---------------- pass 1: bin edges into 512-node buckets (LDS count + segment write) ----
__launch_bounds__(256)
__global__ void k_bin(const int* __restrict__ src, const int* __restrict__ dst,
                      int E, int nbuck, int capB,
                      int* __restrict__ cursor, int* __restrict__ binned){
  __shared__ int cnt[128];
  __shared__ int segbase[128];
  const int tid = threadIdx.x;
  for (int t = tid; t < nbuck; t += 256) cnt[t] = 0;
  __syncthreads();
  const int e0 = blockIdx.x*4096 + tid;
  int pk[16], bk[16];
#pragma unroll
  for (int j = 0; j < 16; j++){
    int e = e0 + j*256;
    if (e < E){
      int d = dst[e], s = src[e];
      bk[j] = d >> 9;
      pk[j] = (s << 9) | (d & 511);
      atomicAdd(&cnt[bk[j]], 1);
    } else bk[j] = -1;
  }
  __syncthreads();
  for (int t = tid; t < nbuck; t += 256){
    int c = cnt[t];
    if (c > 0) segbase[t] = t*capB + atomicAdd(&cursor[t], c);
    cnt[t] = 0;
  }
  __syncthreads();
#pragma unroll
  for (int j = 0; j < 16; j++){
    if (bk[j] >= 0){
      int ord = atomicAdd(&cnt[bk[j]], 1);
      binned[segbase[bk[j]] + ord] = pk[j];
    }
  }
}

// ---------------- pass 2: per-bucket CSR, neighbor lists SRC-OCTILE-ORDERED ----------------
// All agg waves sweep octiles in lockstep -> gather working set ~2MB, L2-resident per XCD.
__launch_bounds__(256)
__global__ void k_build(const int* __restrict__ binned, const int* __restrict__ cursor,
                        int N, int capB, int capC,
                        int2* __restrict__ sd, int* __restrict__ csr){
  __shared__ int deg2[512*8];   // per (dstLow, octile) count
  __shared__ int lst2[512*8];   // per (dstLow, octile) local start
  __shared__ int cnt2[512*8];
  __shared__ int scn[256];
  const int b = blockIdx.x, tid = threadIdx.x;
  for (int t = tid; t < 512*8; t += 256){ deg2[t] = 0; cnt2[t] = 0; }
  __syncthreads();
  const int nE = cursor[b];
  const int gbase = b*capB;
  for (int i = tid; i < nE; i += 256){
    int v = binned[gbase + i];
    int o = v >> (9 + OSH);            // src octile (src>>OSH), fits 0..7 for N<=65535
    if (o > 7) o = 7;
    atomicAdd(&deg2[((v & 511) << 3) + o], 1);
  }
  __syncthreads();
  int d0 = 0, d1 = 0;
#pragma unroll
  for (int o = 0; o < 8; o++){ d0 += deg2[((2*tid) << 3) + o]; d1 += deg2[((2*tid+1) << 3) + o]; }
  const int p0 = (d0+7)&~7, p1 = (d1+7)&~7;
  scn[tid] = p0 + p1;
  __syncthreads();
#pragma unroll
  for (int off = 1; off < 256; off <<= 1){
    int add = (tid >= off) ? scn[tid-off] : 0;
    __syncthreads();
    scn[tid] += add;
    __syncthreads();
  }
  const int ex = scn[tid] - (p0 + p1);
  const int csrb = b*capC;
  {
    int off0 = ex;
#pragma unroll
    for (int o = 0; o < 8; o++){ lst2[((2*tid) << 3) + o] = off0; off0 += deg2[((2*tid) << 3) + o]; }
    int off1 = ex + p0;
#pragma unroll
    for (int o = 0; o < 8; o++){ lst2[((2*tid+1) << 3) + o] = off1; off1 += deg2[((2*tid+1) << 3) + o]; }
  }
  const int n0 = b*512 + 2*tid, n1 = n0 + 1;
  if (n0 < N) sd[n0] = make_int2(csrb + ex, p0);
  if (n1 < N) sd[n1] = make_int2(csrb + ex + p0, p1);
  __syncthreads();
  for (int i = tid; i < nE; i += 256){
    int v = binned[gbase + i];
    int dl = v & 511, s = v >> 9;
    int o = s >> OSH; if (o > 7) o = 7;
    int ord = atomicAdd(&cnt2[(dl << 3) + o], 1);
    csr[csrb + lst2[(dl << 3) + o] + ord] = s;
  }
  for (int j = d0; j < p0; j++) csr[csrb + ex + j] = N;
  for (int j = d1; j < p1; j++) csr[csrb + ex + p0 + j] = N;
}

// ---------------- fp16 MFMA GEMM, 144 cols: H/z (cols 0-127) + head dots (128-140) ----------------
// 64 rows/block; waves 0,1: col-tiles 0-3; waves 2,3: col-tiles 4-8.
// A-frags for all 4 k-chunks prefetched up front (8 independent loads).
// NOTE: ct loops must stay compile-time (runtime trip count -> acc demoted to scratch, R5).
__launch_bounds__(256)
__global__ void k_gemm_mfma(const void* __restrict__ Xin, const _Float16* __restrict__ Wt,
                            const float* __restrict__ bias, void* __restrict__ Hout,
                            float* __restrict__ dsws,
                            int M, int in_fp32, int out_fp32, int zero_pad){
  const int wave = threadIdx.x >> 6;
  const int lane = threadIdx.x & 63;
  const int quad = lane >> 4;
  const int l16  = lane & 15;
  const int rbase = blockIdx.x*64 + (wave & 1)*32;
  const int cthi = wave >> 1;          // 0: tiles 0-3, 1: tiles 4-8
  const int ctb = cthi*4;

  const _Float16* X16 = (const _Float16*)Xin;
  const float*    X32 = (const float*)Xin;

  half8 af[4][2];
#pragma unroll
  for (int kc = 0; kc < 4; kc++){
#pragma unroll
    for (int rt = 0; rt < 2; rt++){
      int r = rbase + rt*16 + l16;
      r = (r < M) ? r : (M - 1);
      if (in_fp32){
        const float* p = X32 + (size_t)r*128 + kc*32 + quad*8;
        float4 f0 = *(const float4*)p;
        float4 f1 = *(const float4*)(p + 4);
        half8 a;
        a[0]=(_Float16)f0.x; a[1]=(_Float16)f0.y; a[2]=(_Float16)f0.z; a[3]=(_Float16)f0.w;
        a[4]=(_Float16)f1.x; a[5]=(_Float16)f1.y; a[6]=(_Float16)f1.z; a[7]=(_Float16)f1.w;
        af[kc][rt] = a;
      } else {
        af[kc][rt] = *(const half8*)(X16 + (size_t)r*128 + kc*32 + quad*8);
      }
    }
  }

  floatx4 acc[2][5] = {};
#pragma unroll
  for (int kc = 0; kc < 4; kc++){
#pragma unroll
    for (int ct = 0; ct < 5; ct++){
      if (ct == 4 && cthi == 0) continue;     // wave-uniform skip; indices stay constant
      half8 bf = *(const half8*)(Wt + (size_t)((ctb+ct)*16 + l16)*128 + kc*32 + quad*8);
      acc[0][ct] = __builtin_amdgcn_mfma_f32_16x16x32_f16(af[kc][0], bf, acc[0][ct], 0, 0, 0);
      acc[1][ct] = __builtin_amdgcn_mfma_f32_16x16x32_f16(af[kc][1], bf, acc[1][ct], 0, 0, 0);
    }
  }
#pragma unroll
  for (int rt = 0; rt < 2; rt++){
#pragma unroll
    for (int ct = 0; ct < 5; ct++){
      if (ct == 4 && cthi == 0) continue;
      int col = (ctb+ct)*16 + l16;
      float bv = (col < 128) ? bias[col] : 0.f;
#pragma unroll
      for (int reg = 0; reg < 4; reg++){
        int r = rbase + rt*16 + quad*4 + reg;
        if (r < M){
          float v = acc[rt][ct][reg] + bv;
          if (col < 128){
            if (out_fp32) ((float*)Hout)[(size_t)r*128 + col] = v;
            else          ((_Float16*)Hout)[(size_t)r*128 + col] = (_Float16)v;
          } else if (col < 141){
            dsws[(size_t)(col-128)*M + r] = v;
          }
        } else if (zero_pad && r == M && !out_fp32 && col < 128){
          ((_Float16*)Hout)[(size_t)r*128 + col] = (_Float16)0.f;
        }
      }
    }
  }
}

// ---------------- minimal gather-sum (+ fused se3 for previous layer) ----------------
__launch_bounds__(256)
__global__ void k_agg(const _Float16* __restrict__ H, const int* __restrict__ csr,
                      const int2* __restrict__ sd, _Float16* __restrict__ Xout,
                      int N, int agg_blocks,
                      const float* __restrict__ dsws, const float* __restrict__ bc,
                      const float* __restrict__ bR, const float* __restrict__ bt,
                      const float* __restrict__ pos_in, float* __restrict__ pos_o,
                      float* __restrict__ R_o, float* __restrict__ t_o, int se3_layer){
  if ((int)blockIdx.x >= agg_blocks){
    int n = (blockIdx.x - agg_blocks)*256 + threadIdx.x;
    if (n < N) se3_node(n, dsws, bc, bR, bt, pos_in, pos_o, R_o, t_o, se3_layer, N);
    return;
  }
  const int wave = threadIdx.x >> 6;
  const int lane = threadIdx.x & 63;
  const int node = blockIdx.x*4 + wave;
  if (node >= N) return;
  int2 s = sd[node];
  const int s0 = s.x, degp = s.y;
  const unsigned int* Hu = (const unsigned int*)H;   // half2/uint; row = 64 uints
  float acc0 = 0.f, acc1 = 0.f;
  for (int base = 0; base < degp; base += 64){
    int myidx = csr[s0 + base + lane];               // one coalesced load covers 64 edges
    int m = degp - base; m = (m < 64) ? m : 64;      // multiple of 8
    for (int k = 0; k < m; k += 8){
      unsigned int v[8];
#pragma unroll
      for (int j = 0; j < 8; j++){
        int idx = __builtin_amdgcn_readlane(myidx, k + j);   // SGPR row index
        v[j] = Hu[(size_t)idx*64 + lane];
      }
#pragma unroll
      for (int j = 0; j < 8; j++){
        float2 f = __half22float2(*(__half2*)&v[j]);
        acc0 += f.x; acc1 += f.y;
      }
    }
  }
  __half2 ho = __floats2half2_rn(acc0, acc1);
  ((unsigned int*)Xout)[(size_t)node*64 + lane] = *(unsigned int*)&ho;
}

// ---------------- standalone se3 (final layer) ----------------
__launch_bounds__(256)
__global__ void k_se3(const float* __restrict__ dsws,
                      const float* __restrict__ bc, const float* __restrict__ bR,
                      const float* __restrict__ bt, const float* __restrict__ pos_in,
                      float* __restrict__ pos_o, float* __restrict__ R_o, float* __restrict__ t_o,
                      int layer, int N){
  int n = blockIdx.x*256 + threadIdx.x;
  if (n < N) se3_node(n, dsws, bc, bR, bt, pos_in, pos_o, R_o, t_o, layer, N);
}

extern "C" void kernel_launch(void* const* d_in, const int* in_sizes, int n_in,
                              void* d_out, int out_size, void* d_ws, size_t ws_size,
                              hipStream_t stream){
  const float* x0  = (const float*)d_in[0];
  const float* pos = (const float*)d_in[1];
  const int*   ei  = (const int*)d_in[2];
  const float* Wl  = (const float*)d_in[3];
  const float* bl  = (const float*)d_in[4];
  const float* Wc  = (const float*)d_in[5];
  const float* bc  = (const float*)d_in[6];
  const float* WR  = (const float*)d_in[7];
  const float* bR  = (const float*)d_in[8];
  const float* Wt  = (const float*)d_in[9];
  const float* bt  = (const float*)d_in[10];
  const float* Wf  = (const float*)d_in[11];
  const float* bf  = (const float*)d_in[12];

  const int N = in_sizes[0] / 128;
  const int E = in_sizes[2] / 2;
  const int* srcp = ei;
  const int* dstp = ei + E;

  float* z_out = (float*)d_out;
  float* pos_o = z_out + (size_t)N*128;
  float* R_o   = pos_o + (size_t)N*3;
  float* t_o   = R_o   + (size_t)N*9;

  const int nbuck = (N + 511) >> 9;                       // 512-node buckets (<=128)
  const int capB  = (((E + nbuck - 1)/nbuck)*5/4 + 256 + 63) & ~63;  // binned capacity/bucket
  const int capC  = capB + 512*7;                          // csr capacity/bucket (max padding)

  char* ws = (char*)d_ws;
  size_t off = 0;
  auto alloc = [&](size_t bytes)->char*{
    char* p = ws + off; off += (bytes + 511) & ~(size_t)511; return p;
  };
  _Float16* buf0h = (_Float16*)alloc((size_t)N*128*2);        // out16 ping
  _Float16* buf1h = (_Float16*)alloc((size_t)(N+1)*128*2);    // h16 (+dummy zero row N)
  _Float16* wTx   = (_Float16*)alloc((size_t)4*WCOLS*128*2);
  float* dsws   = (float*)alloc((size_t)13*N*4);
  int2*  sd     = (int2*) alloc((size_t)N*8);
  int*   cursor = (int*)  alloc((size_t)nbuck*4);
  int*   binned = (int*)  alloc((size_t)nbuck*capB*4);
  int*   csr    = (int*)  alloc((size_t)nbuck*capC*4);

  k_prep_w<<<dim3((4*WCOLS*128 + 255)/256), dim3(256), 0, stream>>>(
      Wl, Wf, Wc, WR, Wt, wTx, cursor, nbuck);
  k_bin   <<<dim3((E + 4095)/4096), dim3(256), 0, stream>>>(srcp, dstp, E, nbuck, capB, cursor, binned);
  k_build <<<dim3(nbuck), dim3(256), 0, stream>>>(binned, cursor, N, capB, capC, sd, csr);

  const int gemm_blocks_pad = (N + 64)/64;    // covers dummy row N
  const int gemm_blocks     = (N + 63)/64;
  const int agg_blocks      = (N + 3)/4;
  const int se3_blocks      = (N + 255)/256;

  const void* xcur = (const void*)x0;
  for (int layer = 0; layer < 3; layer++){
    k_gemm_mfma<<<dim3(gemm_blocks_pad), dim3(256), 0, stream>>>(
        xcur, wTx + (size_t)layer*WCOLS*128, bl + (size_t)layer*128, (void*)buf1h,
        dsws, N, (layer == 0) ? 1 : 0, 0, 1);
    int extra = (layer >= 1) ? se3_blocks : 0;
    k_agg<<<dim3(agg_blocks + extra), dim3(256), 0, stream>>>(
        buf1h, csr, sd, buf0h, N, agg_blocks,
        dsws, bc + (layer-1), bR + (size_t)(layer-1)*9, bt + (size_t)(layer-1)*3,
        pos, pos_o, R_o, t_o, layer - 1);
    xcur = (const void*)buf0h;
  }
  k_gemm_mfma<<<dim3(gemm_blocks), dim3(256), 0, stream>>>(
      xcur, wTx + (size_t)3*WCOLS*128, bf, (void*)z_out, dsws, N, 0, 1, 0);
  k_se3<<<dim3(se3_blocks), dim3(256), 0, stream>>>(
      dsws, bc + 2, bR + 18, bt + 6, pos, pos_o, R_o, t_o, 2, N);
}

// Round 9
// 305.059 us; speedup vs baseline: 1.8181x; 1.0449x over previous
//
#include <hip/hip_runtime.h>
#include <hip/hip_fp16.h>

typedef _Float16 half8 __attribute__((ext_vector_type(8)));
typedef float floatx4 __attribute__((ext_vector_type(4)));

#define NHC 16            // head-col block (13 used + 3 pad)
#define WCOLS (128 + NHC) // 144 columns in extended W
#define OSH 13            // src-octile shift (kept from R8; neutral-to-slightly-positive)

// ---------------- QR: 3x3 Householder, LAPACK sgeqrf/sorgqr convention ----------------
__device__ inline void qr3_q(const double A[3][3], double Q[3][3]){
  double a[3][3];
#pragma unroll
  for (int r = 0; r < 3; r++)
#pragma unroll
    for (int c = 0; c < 3; c++) a[r][c] = A[r][c];

  double v1[3] = {1.0, 0.0, 0.0};
  double tau1 = 0.0;
  {
    double xn2 = a[1][0]*a[1][0] + a[2][0]*a[2][0];
    if (xn2 != 0.0){
      double alpha = a[0][0];
      double beta = -copysign(sqrt(alpha*alpha + xn2), alpha);
      tau1 = (beta - alpha) / beta;
      double inv = 1.0 / (alpha - beta);
      v1[1] = a[1][0] * inv;
      v1[2] = a[2][0] * inv;
#pragma unroll
      for (int c = 1; c < 3; c++){
        double w = a[0][c] + v1[1]*a[1][c] + v1[2]*a[2][c];
        double tw = tau1 * w;
        a[0][c] -= tw;
        a[1][c] -= tw * v1[1];
        a[2][c] -= tw * v1[2];
      }
    }
  }
  double tau2 = 0.0, v2 = 0.0;
  {
    double x2 = a[2][1];
    if (x2 != 0.0){
      double alpha = a[1][1];
      double beta = -copysign(sqrt(alpha*alpha + x2*x2), alpha);
      tau2 = (beta - alpha) / beta;
      v2 = x2 / (alpha - beta);
    }
  }
  double M[3][3] = {{1.0, 0.0, 0.0},
                    {0.0, 1.0 - tau2, -tau2*v2},
                    {0.0, -tau2*v2, 1.0 - tau2*v2*v2}};
#pragma unroll
  for (int c = 0; c < 3; c++){
    double w = v1[0]*M[0][c] + v1[1]*M[1][c] + v1[2]*M[2][c];
#pragma unroll
    for (int r = 0; r < 3; r++)
      Q[r][c] = M[r][c] - tau1 * v1[r] * w;
  }
}

// ---------------- SE(3) per-node epilogue from a local ds[13] ----------------
__device__ inline void se3_node_ds(int n, const float ds[13],
                                   const float* __restrict__ bc, const float* __restrict__ bR,
                                   const float* __restrict__ bt, const float* __restrict__ pos_in,
                                   float* __restrict__ pos_o, float* __restrict__ R_o,
                                   float* __restrict__ t_o, int layer){
  double A[3][3], Q[3][3];
#pragma unroll
  for (int r = 0; r < 3; r++)
#pragma unroll
    for (int c = 0; c < 3; c++)
      A[r][c] = (double)ds[1 + r*3 + c] + (double)bR[r*3 + c];
  qr3_q(A, Q);

  double pd = (double)ds[0] + (double)bc[0];
#pragma unroll
  for (int c = 0; c < 3; c++){
    double base = (layer == 0) ? (double)pos_in[n*3 + c] : (double)pos_o[n*3 + c];
    pos_o[n*3 + c] = (float)(base + pd);
  }

  if (layer == 0){
#pragma unroll
    for (int r = 0; r < 3; r++)
#pragma unroll
      for (int c = 0; c < 3; c++)
        R_o[n*9 + r*3 + c] = (float)Q[r][c];
  } else {
    double Rold[3][3];
#pragma unroll
    for (int r = 0; r < 3; r++)
#pragma unroll
      for (int c = 0; c < 3; c++)
        Rold[r][c] = (double)R_o[n*9 + r*3 + c];
#pragma unroll
    for (int r = 0; r < 3; r++)
#pragma unroll
      for (int c = 0; c < 3; c++){
        double s = Q[r][0]*Rold[0][c] + Q[r][1]*Rold[1][c] + Q[r][2]*Rold[2][c];
        R_o[n*9 + r*3 + c] = (float)s;
      }
  }
#pragma unroll
  for (int c = 0; c < 3; c++){
    double base = (layer == 0) ? 0.0 : (double)t_o[n*3 + c];
    t_o[n*3 + c] = (float)(base + (double)ds[10 + c] + (double)bt[c]);
  }
}

// ---------------- weight prep (+ cursor zero-init, fused) ----------------
__global__ void k_prep_w(const float* __restrict__ Wl, const float* __restrict__ Wf,
                         const float* __restrict__ Wc, const float* __restrict__ WR,
                         const float* __restrict__ Wt, _Float16* __restrict__ wTx,
                         int* __restrict__ cursor, int nbuck){
  int t = blockIdx.x*256 + threadIdx.x;
  if (blockIdx.x == 0 && threadIdx.x < nbuck) cursor[threadIdx.x] = 0;
  if (t >= 4*WCOLS*128) return;
  int l = t / (WCOLS*128);
  int rem = t - l*(WCOLS*128);
  int n = rem >> 7;
  int k = rem & 127;
  float v = 0.f;
  if (n < 128){
    const float* W = (l < 3) ? (Wl + (size_t)l*16384) : Wf;
    v = W[k*128 + n];
  } else if (l > 0){
    int h = n - 128, hl = l - 1;
    if (h == 0)       v = Wc[(size_t)hl*128 + k];
    else if (h < 10)  v = WR[(size_t)hl*128*9 + k*9 + (h-1)];
    else if (h < 13)  v = Wt[(size_t)hl*128*3 + k*3 + (h-10)];
  }
  wTx[t] = (_Float16)v;
}

// ---------------- pass 1: bin edges into 512-node buckets ----------------
__launch_bounds__(256)
__global__ void k_bin(const int* __restrict__ src, const int* __restrict__ dst,
                      int E, int nbuck, int capB,
                      int* __restrict__ cursor, int* __restrict__ binned){
  __shared__ int cnt[128];
  __shared__ int segbase[128];
  const int tid = threadIdx.x;
  for (int t = tid; t < nbuck; t += 256) cnt[t] = 0;
  __syncthreads();
  const int e0 = blockIdx.x*4096 + tid;
  int pk[16], bk[16];
#pragma unroll
  for (int j = 0; j < 16; j++){
    int e = e0 + j*256;
    if (e < E){
      int d = dst[e], s = src[e];
      bk[j] = d >> 9;
      pk[j] = (s << 9) | (d & 511);
      atomicAdd(&cnt[bk[j]], 1);
    } else bk[j] = -1;
  }
  __syncthreads();
  for (int t = tid; t < nbuck; t += 256){
    int c = cnt[t];
    if (c > 0) segbase[t] = t*capB + atomicAdd(&cursor[t], c);
    cnt[t] = 0;
  }
  __syncthreads();
#pragma unroll
  for (int j = 0; j < 16; j++){
    if (bk[j] >= 0){
      int ord = atomicAdd(&cnt[bk[j]], 1);
      binned[segbase[bk[j]] + ord] = pk[j];
    }
  }
}

// ---------------- pass 2: per-bucket CSR, src-octile-ordered neighbor lists ----------------
__launch_bounds__(256)
__global__ void k_build(const int* __restrict__ binned, const int* __restrict__ cursor,
                        int N, int capB, int capC,
                        int2* __restrict__ sd, int* __restrict__ csr){
  __shared__ int deg2[512*8];
  __shared__ int lst2[512*8];
  __shared__ int cnt2[512*8];
  __shared__ int scn[256];
  const int b = blockIdx.x, tid = threadIdx.x;
  for (int t = tid; t < 512*8; t += 256){ deg2[t] = 0; cnt2[t] = 0; }
  __syncthreads();
  const int nE = cursor[b];
  const int gbase = b*capB;
  for (int i = tid; i < nE; i += 256){
    int v = binned[gbase + i];
    int o = v >> (9 + OSH);
    if (o > 7) o = 7;
    atomicAdd(&deg2[((v & 511) << 3) + o], 1);
  }
  __syncthreads();
  int d0 = 0, d1 = 0;
#pragma unroll
  for (int o = 0; o < 8; o++){ d0 += deg2[((2*tid) << 3) + o]; d1 += deg2[((2*tid+1) << 3) + o]; }
  const int p0 = (d0+7)&~7, p1 = (d1+7)&~7;
  scn[tid] = p0 + p1;
  __syncthreads();
#pragma unroll
  for (int off = 1; off < 256; off <<= 1){
    int add = (tid >= off) ? scn[tid-off] : 0;
    __syncthreads();
    scn[tid] += add;
    __syncthreads();
  }
  const int ex = scn[tid] - (p0 + p1);
  const int csrb = b*capC;
  {
    int off0 = ex;
#pragma unroll
    for (int o = 0; o < 8; o++){ lst2[((2*tid) << 3) + o] = off0; off0 += deg2[((2*tid) << 3) + o]; }
    int off1 = ex + p0;
#pragma unroll
    for (int o = 0; o < 8; o++){ lst2[((2*tid+1) << 3) + o] = off1; off1 += deg2[((2*tid+1) << 3) + o]; }
  }
  const int n0 = b*512 + 2*tid, n1 = n0 + 1;
  if (n0 < N) sd[n0] = make_int2(csrb + ex, p0);
  if (n1 < N) sd[n1] = make_int2(csrb + ex + p0, p1);
  __syncthreads();
  for (int i = tid; i < nE; i += 256){
    int v = binned[gbase + i];
    int dl = v & 511, s = v >> 9;
    int o = s >> OSH; if (o > 7) o = 7;
    int ord = atomicAdd(&cnt2[(dl << 3) + o], 1);
    csr[csrb + lst2[(dl << 3) + o] + ord] = s;
  }
  for (int j = d0; j < p0; j++) csr[csrb + ex + j] = N;
  for (int j = d1; j < p1; j++) csr[csrb + ex + p0 + j] = N;
}

// ---------------- fp16 MFMA GEMM, 144 cols, LDS-staged coalesced epilogue + fused se3 ----
// 64 rows/block; waves 0,1: col-tiles 0-3 (cols 0-63); waves 2,3: col-tiles 4-8 (cols 64-143).
// D-fragments land in LDS; H stored as full-line 16B/lane chunks; heads (cols 128-140) stay
// in LDS and threads 0-63 run the SE(3) epilogue for this block's 64 rows (se3_layer >= 0).
// NOTE: ct loops must stay compile-time (runtime trip count -> acc demoted to scratch, R5).
__launch_bounds__(256)
__global__ void k_gemm_mfma(const void* __restrict__ Xin, const _Float16* __restrict__ Wt,
                            const float* __restrict__ bias, void* __restrict__ Hout,
                            int M, int in_fp32, int out_fp32, int zero_pad,
                            int se3_layer,
                            const float* __restrict__ bc, const float* __restrict__ bR,
                            const float* __restrict__ bt, const float* __restrict__ pos_in,
                            float* __restrict__ pos_o, float* __restrict__ R_o,
                            float* __restrict__ t_o, int N){
  __shared__ __align__(16) unsigned char lds[64*128*4 + 64*16*4];  // H(fp32 worst) + heads
  _Float16* lh = (_Float16*)lds;                 // fp16 H view, stride 128
  float*    lf = (float*)lds;                    // fp32 H view, stride 128
  float*    lheads = (float*)(lds + 64*128*4);   // heads, stride 16

  const int tid  = threadIdx.x;
  const int wave = tid >> 6;
  const int lane = tid & 63;
  const int quad = lane >> 4;
  const int l16  = lane & 15;
  const int rbase0 = blockIdx.x*64;
  const int rbase  = rbase0 + (wave & 1)*32;
  const int cthi = wave >> 1;          // 0: tiles 0-3, 1: tiles 4-8
  const int ctb = cthi*4;

  const _Float16* X16 = (const _Float16*)Xin;
  const float*    X32 = (const float*)Xin;

  half8 af[4][2];
#pragma unroll
  for (int kc = 0; kc < 4; kc++){
#pragma unroll
    for (int rt = 0; rt < 2; rt++){
      int r = rbase + rt*16 + l16;
      r = (r < M) ? r : (M - 1);
      if (in_fp32){
        const float* p = X32 + (size_t)r*128 + kc*32 + quad*8;
        float4 f0 = *(const float4*)p;
        float4 f1 = *(const float4*)(p + 4);
        half8 a;
        a[0]=(_Float16)f0.x; a[1]=(_Float16)f0.y; a[2]=(_Float16)f0.z; a[3]=(_Float16)f0.w;
        a[4]=(_Float16)f1.x; a[5]=(_Float16)f1.y; a[6]=(_Float16)f1.z; a[7]=(_Float16)f1.w;
        af[kc][rt] = a;
      } else {
        af[kc][rt] = *(const half8*)(X16 + (size_t)r*128 + kc*32 + quad*8);
      }
    }
  }

  floatx4 acc[2][5] = {};
#pragma unroll
  for (int kc = 0; kc < 4; kc++){
#pragma unroll
    for (int ct = 0; ct < 5; ct++){
      if (ct == 4 && cthi == 0) continue;     // wave-uniform skip; indices stay constant
      half8 bf = *(const half8*)(Wt + (size_t)((ctb+ct)*16 + l16)*128 + kc*32 + quad*8);
      acc[0][ct] = __builtin_amdgcn_mfma_f32_16x16x32_f16(af[kc][0], bf, acc[0][ct], 0, 0, 0);
      acc[1][ct] = __builtin_amdgcn_mfma_f32_16x16x32_f16(af[kc][1], bf, acc[1][ct], 0, 0, 0);
    }
  }

  // ---- stage D-fragments to LDS ----
#pragma unroll
  for (int rt = 0; rt < 2; rt++){
#pragma unroll
    for (int ct = 0; ct < 5; ct++){
      if (ct == 4 && cthi == 0) continue;
      int col = (ctb+ct)*16 + l16;
#pragma unroll
      for (int reg = 0; reg < 4; reg++){
        int rl = (wave & 1)*32 + rt*16 + quad*4 + reg;   // 0..63 local row
        float v = acc[rt][ct][reg];
        if (col < 128){
          v += bias[col];
          if (out_fp32) lf[rl*128 + col] = v;
          else          lh[rl*128 + col] = (_Float16)v;
        } else {
          lheads[rl*16 + (col - 128)] = v;
        }
      }
    }
  }
  __syncthreads();

  // ---- coalesced H store (full 128B lines) ----
  if (out_fp32){
#pragma unroll
    for (int i = 0; i < 8; i++){
      int idx4 = i*256 + tid;            // 2048 float4 chunks
      int row = idx4 >> 5, c4 = idx4 & 31;
      int gr = rbase0 + row;
      if (gr < M)
        *(float4*)((float*)Hout + (size_t)gr*128 + c4*4) = *(const float4*)&lf[row*128 + c4*4];
    }
  } else {
#pragma unroll
    for (int i = 0; i < 4; i++){
      int idx8 = i*256 + tid;            // 1024 half8 chunks
      int row = idx8 >> 4, c8 = idx8 & 15;
      int gr = rbase0 + row;
      if (gr < M){
        *(half8*)((_Float16*)Hout + (size_t)gr*128 + c8*8) = *(const half8*)&lh[row*128 + c8*8];
      } else if (zero_pad && gr == M){
        half8 z = {};
        *(half8*)((_Float16*)Hout + (size_t)gr*128 + c8*8) = z;
      }
    }
  }

  // ---- fused SE(3) epilogue for this block's rows ----
  if (se3_layer >= 0 && tid < 64){
    int n = rbase0 + tid;
    if (n < N){
      float ds[13];
#pragma unroll
      for (int c = 0; c < 13; c++) ds[c] = lheads[tid*16 + c];
      se3_node_ds(n, ds, bc, bR, bt, pos_in, pos_o, R_o, t_o, se3_layer);
    }
  }
}

// ---------------- minimal gather-sum ----------------
__launch_bounds__(256)
__global__ void k_agg(const _Float16* __restrict__ H, const int* __restrict__ csr,
                      const int2* __restrict__ sd, _Float16* __restrict__ Xout, int N){
  const int wave = threadIdx.x >> 6;
  const int lane = threadIdx.x & 63;
  const int node = blockIdx.x*4 + wave;
  if (node >= N) return;
  int2 s = sd[node];
  const int s0 = s.x, degp = s.y;
  const unsigned int* Hu = (const unsigned int*)H;   // half2/uint; row = 64 uints
  float acc0 = 0.f, acc1 = 0.f;
  for (int base = 0; base < degp; base += 64){
    int myidx = csr[s0 + base + lane];               // one coalesced load covers 64 edges
    int m = degp - base; m = (m < 64) ? m : 64;      // multiple of 8
    for (int k = 0; k < m; k += 8){
      unsigned int v[8];
#pragma unroll
      for (int j = 0; j < 8; j++){
        int idx = __builtin_amdgcn_readlane(myidx, k + j);   // SGPR row index
        v[j] = Hu[(size_t)idx*64 + lane];
      }
#pragma unroll
      for (int j = 0; j < 8; j++){
        float2 f = __half22float2(*(__half2*)&v[j]);
        acc0 += f.x; acc1 += f.y;
      }
    }
  }
  __half2 ho = __floats2half2_rn(acc0, acc1);
  ((unsigned int*)Xout)[(size_t)node*64 + lane] = *(unsigned int*)&ho;
}

extern "C" void kernel_launch(void* const* d_in, const int* in_sizes, int n_in,
                              void* d_out, int out_size, void* d_ws, size_t ws_size,
                              hipStream_t stream){
  const float* x0  = (const float*)d_in[0];
  const float* pos = (const float*)d_in[1];
  const int*   ei  = (const int*)d_in[2];
  const float* Wl  = (const float*)d_in[3];
  const float* bl  = (const float*)d_in[4];
  const float* Wc  = (const float*)d_in[5];
  const float* bc  = (const float*)d_in[6];
  const float* WR  = (const float*)d_in[7];
  const float* bR  = (const float*)d_in[8];
  const float* Wt  = (const float*)d_in[9];
  const float* bt  = (const float*)d_in[10];
  const float* Wf  = (const float*)d_in[11];
  const float* bf  = (const float*)d_in[12];

  const int N = in_sizes[0] / 128;
  const int E = in_sizes[2] / 2;
  const int* srcp = ei;
  const int* dstp = ei + E;

  float* z_out = (float*)d_out;
  float* pos_o = z_out + (size_t)N*128;
  float* R_o   = pos_o + (size_t)N*3;
  float* t_o   = R_o   + (size_t)N*9;

  const int nbuck = (N + 511) >> 9;
  const int capB  = (((E + nbuck - 1)/nbuck)*5/4 + 256 + 63) & ~63;
  const int capC  = capB + 512*7;

  char* ws = (char*)d_ws;
  size_t off = 0;
  auto alloc = [&](size_t bytes)->char*{
    char* p = ws + off; off += (bytes + 511) & ~(size_t)511; return p;
  };
  _Float16* buf0h = (_Float16*)alloc((size_t)N*128*2);        // out16 ping
  _Float16* buf1h = (_Float16*)alloc((size_t)(N+1)*128*2);    // h16 (+dummy zero row N)
  _Float16* wTx   = (_Float16*)alloc((size_t)4*WCOLS*128*2);
  int2*  sd     = (int2*) alloc((size_t)N*8);
  int*   cursor = (int*)  alloc((size_t)nbuck*4);
  int*   binned = (int*)  alloc((size_t)nbuck*capB*4);
  int*   csr    = (int*)  alloc((size_t)nbuck*capC*4);

  k_prep_w<<<dim3((4*WCOLS*128 + 255)/256), dim3(256), 0, stream>>>(
      Wl, Wf, Wc, WR, Wt, wTx, cursor, nbuck);
  k_bin   <<<dim3((E + 4095)/4096), dim3(256), 0, stream>>>(srcp, dstp, E, nbuck, capB, cursor, binned);
  k_build <<<dim3(nbuck), dim3(256), 0, stream>>>(binned, cursor, N, capB, capC, sd, csr);

  const int gemm_blocks_pad = (N + 64)/64;    // covers dummy row N
  const int gemm_blocks     = (N + 63)/64;
  const int agg_blocks      = (N + 3)/4;

  const void* xcur = (const void*)x0;
  for (int layer = 0; layer < 3; layer++){
    // GEMM layer `layer`; epilogue also computes head dots + SE(3) of layer-1
    k_gemm_mfma<<<dim3(gemm_blocks_pad), dim3(256), 0, stream>>>(
        xcur, wTx + (size_t)layer*WCOLS*128, bl + (size_t)layer*128, (void*)buf1h,
        N, (layer == 0) ? 1 : 0, 0, 1,
        layer - 1, bc + (layer-1), bR + (size_t)(layer-1)*9, bt + (size_t)(layer-1)*3,
        pos, pos_o, R_o, t_o, N);
    k_agg<<<dim3(agg_blocks), dim3(256), 0, stream>>>(buf1h, csr, sd, buf0h, N);
    xcur = (const void*)buf0h;
  }
  // final GEMM (z, fp32) + heads of layer 2 + SE(3) layer 2
  k_gemm_mfma<<<dim3(gemm_blocks), dim3(256), 0, stream>>>(
      xcur, wTx + (size_t)3*WCOLS*128, bf, (void*)z_out,
      N, 0, 1, 0,
      2, bc + 2, bR + 18, bt + 6,
      pos, pos_o, R_o, t_o, N);
}